// Round 8
// baseline (715.051 us; speedup 1.0000x reference)
//
#include <hip/hip_runtime.h>

typedef float f2 __attribute__((ext_vector_type(2)));
typedef float f4 __attribute__((ext_vector_type(4)));

#define TT 2048
#define BB 512
#define II 10
#define HH 20
#define CH 16                 // consumer steps per barrier
#define RS 32                 // ring slots = 2 chunks (double buffer)
#define NCHUNK (TT / CH)      // 128

#define LOG2E 1.44269504088896340736f

__device__ __forceinline__ float fexp2(float x) {
#if __has_builtin(__builtin_amdgcn_exp2f)
    return __builtin_amdgcn_exp2f(x);
#else
    return exp2f(x);
#endif
}

// One block = 2 waves per (direction, sample) sequence.
// Wave 0 (consumer): the serial scan. Lane j (j<20) owns hidden unit j and
//   computes all 4 gate recurrent dots. h-allgather is 20 uniform-index
//   ds_bpermute pulls (one LDS-pipe traversal, no write->read RAW stall).
// Wave 1 (producer): computes xproj[t] = b + W_ih x[t] for all t, writing
//   f4 per unit into a 32-slot LDS ring (double-buffered, 1 barrier/16 steps).
// All gate rows are pre-scaled by -log2e (-2log2e for the g row) so
// activations use v_exp_f32 (2^x) directly with no base-conversion mul.
__global__ __launch_bounds__(128) void lstm_bidir(
    const float* __restrict__ x,
    const float* __restrict__ w_ih_f, const float* __restrict__ w_hh_f,
    const float* __restrict__ b_ih_f, const float* __restrict__ b_hh_f,
    const float* __restrict__ w_ih_r, const float* __restrict__ w_hh_r,
    const float* __restrict__ b_ih_r, const float* __restrict__ b_hh_r,
    float* __restrict__ out)
{
    const int tid  = threadIdx.x;
    const int wid  = tid >> 6;     // 0 = consumer, 1 = producer
    const int lane = tid & 63;
    const int blk  = blockIdx.x;
    const int dir  = blk >> 9;     // 0 = forward, 1 = reverse
    const int s    = blk & 511;    // batch sample

    const float* __restrict__ w_ih = dir ? w_ih_r : w_ih_f;
    const float* __restrict__ w_hh = dir ? w_hh_r : w_hh_f;
    const float* __restrict__ b_ih = dir ? b_ih_r : b_ih_f;
    const float* __restrict__ b_hh = dir ? b_hh_r : b_hh_f;

    const bool valid = (lane < HH);
    const int  j     = valid ? lane : (HH - 1);   // clamp keeps loads in-bounds

    const int t0    = dir ? (TT - 1) : 0;
    const int xstep = dir ? -(BB * II) : (BB * II);
    const int ostep = dir ? -(BB * 2 * HH) : (BB * 2 * HH);
    const int xbase = (t0 * BB + s) * II;

    // Row scale per gate (i,f,g,o): sigmoid rows -log2e, tanh row -2log2e.
    const float gsc[4] = { -LOG2E, -LOG2E, -2.0f * LOG2E, -LOG2E };

    __shared__ f4 ring[RS][HH];   // xproj ring: [slot][unit] = scaled pre-acts

    if (wid == 1) {
        // ---------------- producer wave ----------------
        f2 wih[4][5];
        float bs[4];
#pragma unroll
        for (int g = 0; g < 4; ++g) {
            const int r = g * HH + j;
#pragma unroll
            for (int k = 0; k < 5; ++k) {
                f2 w = *(const f2*)(w_ih + r * II + 2 * k);
                wih[g][k] = w * gsc[g];
            }
            bs[g] = (b_ih[r] + b_hh[r]) * gsc[g];
        }

        auto produce8 = [&](int base) {
            f2 xb[8][5];
#pragma unroll
            for (int i = 0; i < 8; ++i) {
                int u = base + i; if (u > TT - 1) u = TT - 1;   // in-bounds clamp
                const float* px = x + (xbase + u * xstep);
#pragma unroll
                for (int k = 0; k < 5; ++k) xb[i][k] = *(const f2*)(px + 2 * k);
            }
#pragma unroll
            for (int i = 0; i < 8; ++i) {
                const int u = base + i;
                if (u < TT) {
                    f4 xp;
#pragma unroll
                    for (int g = 0; g < 4; ++g) {
                        f2 p = {bs[g], 0.f};
#pragma unroll
                        for (int k = 0; k < 5; ++k) p += wih[g][k] * xb[i][k];
                        xp[g] = p[0] + p[1];
                    }
                    if (valid) ring[u & (RS - 1)][j] = xp;
                }
            }
        };

        produce8(0);              // prefill steps 0..15
        produce8(8);
        for (int chunk = 0; chunk < NCHUNK; ++chunk) {
            __syncthreads();
            const int base = (chunk + 1) * CH;   // fill next chunk's half
            produce8(base);
            produce8(base + 8);
        }
    } else {
        // ---------------- consumer wave (the serial scan) ----------------
        f2 whh[4][10];
#pragma unroll
        for (int g = 0; g < 4; ++g) {
            const int r = g * HH + j;
#pragma unroll
            for (int k = 0; k < 10; ++k) {
                f2 w = *(const f2*)(w_hh + r * HH + 2 * k);
                whh[g][k] = w * gsc[g];
            }
        }

        float c = 0.0f, h = 0.0f;
        int ooff = (t0 * BB + s) * (2 * HH) + dir * HH + j;
        int t = 0;

        for (int chunk = 0; chunk < NCHUNK; ++chunk) {
            __syncthreads();
            f4 xp = ring[t & (RS - 1)][j];   // first step of chunk
#pragma unroll
            for (int i = 0; i < CH; ++i, ++t) {
                // ---- h all-gather: 20 uniform ds_bpermute pulls (1 traversal) ----
                float hg[HH];
#pragma unroll
                for (int k = 0; k < HH; ++k)
                    hg[k] = __builtin_bit_cast(float,
                              __builtin_amdgcn_ds_bpermute(
                                  k * 4, __builtin_bit_cast(int, h)));

                // ---- recurrent dots: 4 gates x 10 pk-FMA ----
                f2 a0[4], a1[4];
#pragma unroll
                for (int g = 0; g < 4; ++g) { a0[g] = f2{0.f, 0.f}; a1[g] = f2{0.f, 0.f}; }
#pragma unroll
                for (int k = 0; k < 5; ++k) {
                    f2 lo; lo[0] = hg[4 * k];     lo[1] = hg[4 * k + 1];
                    f2 hi; hi[0] = hg[4 * k + 2]; hi[1] = hg[4 * k + 3];
#pragma unroll
                    for (int g = 0; g < 4; ++g) {
                        a0[g] += whh[g][2 * k]     * lo;
                        a1[g] += whh[g][2 * k + 1] * hi;
                    }
                }
                float u[4];
#pragma unroll
                for (int g = 0; g < 4; ++g) {
                    const f2 a = a0[g] + a1[g];
                    u[g] = (xp[g] + a[0]) + a[1];   // u is pre-scaled: exp2-ready
                }

                // ---- activations: sg = sigma(v) via rcp(1+2^u) ----
                const float ig = __builtin_amdgcn_rcpf(1.0f + fexp2(u[0]));
                const float fg = __builtin_amdgcn_rcpf(1.0f + fexp2(u[1]));
                const float sg = __builtin_amdgcn_rcpf(1.0f + fexp2(u[2]));  // sigma(2 v_g)
                const float og = __builtin_amdgcn_rcpf(1.0f + fexp2(u[3]));
                const float i2 = ig + ig;
                const float o2 = og + og;

                // ---- lane-local state update (tanh via 2*sigma - 1, FMA form) ----
                const float m = __builtin_fmaf(i2, sg, -ig);        // i * tanh(v_g)
                c = __builtin_fmaf(fg, c, m);
                const float sc_ = __builtin_amdgcn_rcpf(
                                    1.0f + fexp2(c * (-2.0f * LOG2E)));  // sigma(2c)
                h = __builtin_fmaf(o2, sc_, -og);                   // o * tanh(c)

                if (valid) out[ooff] = h;

                // ---- ring read for next step (slack ~ a full step) ----
                if (i < CH - 1) xp = ring[(t + 1) & (RS - 1)][j];
                ooff += ostep;
            }
        }
    }
}

extern "C" void kernel_launch(void* const* d_in, const int* in_sizes, int n_in,
                              void* d_out, int out_size, void* d_ws, size_t ws_size,
                              hipStream_t stream) {
    const float* xp     = (const float*)d_in[0];
    const float* w_ih_f = (const float*)d_in[1];
    const float* w_hh_f = (const float*)d_in[2];
    const float* b_ih_f = (const float*)d_in[3];
    const float* b_hh_f = (const float*)d_in[4];
    const float* w_ih_r = (const float*)d_in[5];
    const float* w_hh_r = (const float*)d_in[6];
    const float* b_ih_r = (const float*)d_in[7];
    const float* b_hh_r = (const float*)d_in[8];
    float* outp = (float*)d_out;

    hipLaunchKernelGGL(lstm_bidir, dim3(1024), dim3(128), 0, stream,
                       xp, w_ih_f, w_hh_f, b_ih_f, b_hh_f,
                       w_ih_r, w_hh_r, b_ih_r, b_hh_r, outp);
}

// Round 9
// 524.975 us; speedup vs baseline: 1.3621x; 1.3621x over previous
//
#include <hip/hip_runtime.h>

typedef float f2 __attribute__((ext_vector_type(2)));
typedef float f4 __attribute__((ext_vector_type(4)));

#define TT 2048
#define BB 512
#define II 10
#define HH 20
#define CH 16                 // consumer steps per barrier / history depth
#define RS 32                 // ring slots = 2 chunks (double buffer)
#define NCHUNK (TT / CH)      // 128

#define LOG2E 1.44269504088896340736f

__device__ __forceinline__ float fexp2(float x) {
#if __has_builtin(__builtin_amdgcn_exp2f)
    return __builtin_amdgcn_exp2f(x);
#else
    return exp2f(x);
#endif
}

// One block = 2 waves per (direction, sample) sequence.
// Wave 0 (consumer): the serial scan at s_setprio(1). Lane j (j<20) owns
//   hidden unit j, computes all 4 gate recurrent dots. Per step: ds_write h
//   into hstage[i][lane] (16-step history, doubles as broadcast buffer),
//   5x ds_read_b128 broadcast, NO global store on the chain.
// Wave 1 (producer): xproj[t] = b + W_ih x[t] into a 32-slot LDS ring.
// Every 16 steps the consumer dumps the staged 16x20 h block to HBM with
// all 64 lanes (5 ds_read_b32 + 5 stores each) -> store vmcnt drain sits
// off the recurrence, register reuse distance = one chunk.
// Gate rows pre-scaled by -log2e (-2log2e for g) so sigma/tanh use v_exp_f32
// (2^x) directly; tanh via 2*sigma-1 in FMA form.
__global__ __launch_bounds__(128) void lstm_bidir(
    const float* __restrict__ x,
    const float* __restrict__ w_ih_f, const float* __restrict__ w_hh_f,
    const float* __restrict__ b_ih_f, const float* __restrict__ b_hh_f,
    const float* __restrict__ w_ih_r, const float* __restrict__ w_hh_r,
    const float* __restrict__ b_ih_r, const float* __restrict__ b_hh_r,
    float* __restrict__ out)
{
    const int tid  = threadIdx.x;
    const int wid  = tid >> 6;     // 0 = consumer, 1 = producer
    const int lane = tid & 63;
    const int blk  = blockIdx.x;
    const int dir  = blk >> 9;     // 0 = forward, 1 = reverse
    const int s    = blk & 511;    // batch sample

    const float* __restrict__ w_ih = dir ? w_ih_r : w_ih_f;
    const float* __restrict__ w_hh = dir ? w_hh_r : w_hh_f;
    const float* __restrict__ b_ih = dir ? b_ih_r : b_ih_f;
    const float* __restrict__ b_hh = dir ? b_hh_r : b_hh_f;

    const bool valid = (lane < HH);
    const int  j     = valid ? lane : (HH - 1);   // clamp keeps loads in-bounds

    const int t0    = dir ? (TT - 1) : 0;
    const int xstep = dir ? -(BB * II) : (BB * II);
    const int ostep = dir ? -(BB * 2 * HH) : (BB * 2 * HH);
    const int xbase = (t0 * BB + s) * II;

    // Row scale per gate (i,f,g,o): sigmoid rows -log2e, tanh row -2log2e.
    const float gsc[4] = { -LOG2E, -LOG2E, -2.0f * LOG2E, -LOG2E };

    __shared__ f4    ring[RS][HH];       // xproj ring: [slot][unit]
    __shared__ float hstage[CH * 64];    // h history: [step-in-chunk][lane]

    if (wid == 1) {
        // ---------------- producer wave ----------------
        f2 wih[4][5];
        float bs[4];
#pragma unroll
        for (int g = 0; g < 4; ++g) {
            const int r = g * HH + j;
#pragma unroll
            for (int k = 0; k < 5; ++k) {
                f2 w = *(const f2*)(w_ih + r * II + 2 * k);
                wih[g][k] = w * gsc[g];
            }
            bs[g] = (b_ih[r] + b_hh[r]) * gsc[g];
        }

        auto produce8 = [&](int base) {
            f2 xb[8][5];
#pragma unroll
            for (int i = 0; i < 8; ++i) {
                int u = base + i; if (u > TT - 1) u = TT - 1;   // in-bounds clamp
                const float* px = x + (xbase + u * xstep);
#pragma unroll
                for (int k = 0; k < 5; ++k) xb[i][k] = *(const f2*)(px + 2 * k);
            }
#pragma unroll
            for (int i = 0; i < 8; ++i) {
                const int u = base + i;
                if (u < TT) {
                    f4 xp;
#pragma unroll
                    for (int g = 0; g < 4; ++g) {
                        f2 p = {bs[g], 0.f};
#pragma unroll
                        for (int k = 0; k < 5; ++k) p += wih[g][k] * xb[i][k];
                        xp[g] = p[0] + p[1];
                    }
                    if (valid) ring[u & (RS - 1)][j] = xp;
                }
            }
        };

        produce8(0);              // prefill steps 0..15
        produce8(8);
        for (int chunk = 0; chunk < NCHUNK; ++chunk) {
            __syncthreads();
            const int base = (chunk + 1) * CH;   // fill next chunk's half
            produce8(base);
            produce8(base + 8);
        }
    } else {
        // ---------------- consumer wave (the serial scan) ----------------
        __builtin_amdgcn_s_setprio(1);

        f2 whh[4][10];
#pragma unroll
        for (int g = 0; g < 4; ++g) {
            const int r = g * HH + j;
#pragma unroll
            for (int k = 0; k < 10; ++k) {
                f2 w = *(const f2*)(w_hh + r * HH + 2 * k);
                whh[g][k] = w * gsc[g];
            }
        }

        // Dump mapping: 320 elements (16 t x 20 j) over 64 lanes x 5.
        const int obase = (t0 * BB + s) * (2 * HH) + dir * HH;
        int offd[5], lds_d[5];
#pragma unroll
        for (int q = 0; q < 5; ++q) {
            const int idx = q * 64 + lane;       // 0..319
            const int td  = idx / HH;            // 0..15
            const int jd  = idx - td * HH;       // 0..19
            offd[q]  = obase + td * ostep + jd;
            lds_d[q] = td * 64 + jd;             // hstage flat index
        }

        f4 hb[5];
#pragma unroll
        for (int k = 0; k < 5; ++k) hb[k] = f4{0.f, 0.f, 0.f, 0.f};

        float c = 0.0f, h = 0.0f;
        int t = 0;

        for (int chunk = 0; chunk < NCHUNK; ++chunk) {
            __syncthreads();
            f4 xp = ring[t & (RS - 1)][j];   // first step of chunk
#pragma unroll
            for (int i = 0; i < CH; ++i, ++t) {
                // ---- recurrent dots: 4 gates x 10 pk-FMA (depends on hb) ----
                f2 a0[4], a1[4];
#pragma unroll
                for (int g = 0; g < 4; ++g) { a0[g] = f2{0.f, 0.f}; a1[g] = f2{0.f, 0.f}; }
#pragma unroll
                for (int k = 0; k < 5; ++k) {
                    const f4 hv = hb[k];
                    f2 lo; lo[0] = hv[0]; lo[1] = hv[1];
                    f2 hi; hi[0] = hv[2]; hi[1] = hv[3];
#pragma unroll
                    for (int g = 0; g < 4; ++g) {
                        a0[g] += whh[g][2 * k]     * lo;
                        a1[g] += whh[g][2 * k + 1] * hi;
                    }
                }
                float u[4];
#pragma unroll
                for (int g = 0; g < 4; ++g) {
                    const f2 a = a0[g] + a1[g];
                    u[g] = (xp[g] + a[0]) + a[1];   // pre-scaled: exp2-ready
                }

                // ---- activations: sigma via rcp(1+2^u) ----
                const float ig = __builtin_amdgcn_rcpf(1.0f + fexp2(u[0]));
                const float fg = __builtin_amdgcn_rcpf(1.0f + fexp2(u[1]));
                const float sg = __builtin_amdgcn_rcpf(1.0f + fexp2(u[2]));  // sigma(2 v_g)
                const float og = __builtin_amdgcn_rcpf(1.0f + fexp2(u[3]));
                const float i2 = ig + ig;
                const float o2 = og + og;

                // ---- lane-local state update (tanh = 2 sigma - 1, FMA form) ----
                const float m = __builtin_fmaf(i2, sg, -ig);        // i * tanh(v_g)
                c = __builtin_fmaf(fg, c, m);
                const float sc_ = __builtin_amdgcn_rcpf(
                                    1.0f + fexp2(c * (-2.0f * LOG2E)));  // sigma(2c)
                h = __builtin_fmaf(o2, sc_, -og);                   // o * tanh(c)

                // ---- stage h (unconditional: lanes >=20 write unread slots) ----
                hstage[i * 64 + lane] = h;
                __builtin_amdgcn_wave_barrier();

                // ---- broadcast read for next step (same-wave LDS is in-order) ----
#pragma unroll
                for (int k = 0; k < 5; ++k)
                    hb[k] = *(const f4*)&hstage[i * 64 + 4 * k];

                // ---- ring read for next step ----
                if (i < CH - 1) xp = ring[(t + 1) & (RS - 1)][j];
            }

            // ---- dump the chunk's 16x20 h block to HBM (off the chain) ----
#pragma unroll
            for (int q = 0; q < 5; ++q) {
                const float v = hstage[lds_d[q]];
                out[offd[q]] = v;
                offd[q] += CH * ostep;
            }
        }
    }
}

extern "C" void kernel_launch(void* const* d_in, const int* in_sizes, int n_in,
                              void* d_out, int out_size, void* d_ws, size_t ws_size,
                              hipStream_t stream) {
    const float* xp     = (const float*)d_in[0];
    const float* w_ih_f = (const float*)d_in[1];
    const float* w_hh_f = (const float*)d_in[2];
    const float* b_ih_f = (const float*)d_in[3];
    const float* b_hh_f = (const float*)d_in[4];
    const float* w_ih_r = (const float*)d_in[5];
    const float* w_hh_r = (const float*)d_in[6];
    const float* b_ih_r = (const float*)d_in[7];
    const float* b_hh_r = (const float*)d_in[8];
    float* outp = (float*)d_out;

    hipLaunchKernelGGL(lstm_bidir, dim3(1024), dim3(128), 0, stream,
                       xp, w_ih_f, w_hh_f, b_ih_f, b_hh_f,
                       w_ih_r, w_hh_r, b_ih_r, b_hh_r, outp);
}

// Round 10
// 506.667 us; speedup vs baseline: 1.4113x; 1.0361x over previous
//
#include <hip/hip_runtime.h>

typedef float f2 __attribute__((ext_vector_type(2)));
typedef float f4 __attribute__((ext_vector_type(4)));

#define TT 2048
#define BB 512
#define II 10
#define HH 20
#define CH 16                 // consumer steps per barrier / history depth
#define RS 32                 // ring slots = 2 chunks (double buffer)
#define NCHUNK (TT / CH)      // 128

#define LOG2E 1.44269504088896340736f

__device__ __forceinline__ float fexp2(float x) {
#if __has_builtin(__builtin_amdgcn_exp2f)
    return __builtin_amdgcn_exp2f(x);
#else
    return exp2f(x);
#endif
}

// One block = 2 waves, handling BOTH directions of ONE sample (s = blockIdx).
// Wave 0 (consumer): lanes 0..19 scan the FORWARD direction, lanes 32..51 the
//   REVERSE direction. Lane (half,j) owns hidden unit j of its direction and
//   computes all 4 gate recurrent dots. Per step: ds_write h into
//   hstage[i][lane], 5x ds_read_b128 of the own half's 20-float row segment.
//   With 512 blocks x 2 waves = 1024 waves on 1024 SIMDs: 1 wave/SIMD,
//   no issue-port co-tenancy on the scan.
// Wave 1 (producer): same half-split; xproj[t] = b + W_ih x[t] into a
//   32-slot LDS ring (per-lane f4), double-buffered, 1 barrier / 16 steps.
// Chunk-end: staged 2x16x20 h block dumped to HBM by all 64 lanes (10 each),
// store vmcnt drain off the recurrence.
// Gate rows pre-scaled by -log2e (-2log2e for g) so sigma/tanh use v_exp_f32
// (2^x) directly; tanh via 2*sigma-1 in FMA form.
__global__ __launch_bounds__(128) void lstm_bidir(
    const float* __restrict__ x,
    const float* __restrict__ w_ih_f, const float* __restrict__ w_hh_f,
    const float* __restrict__ b_ih_f, const float* __restrict__ b_hh_f,
    const float* __restrict__ w_ih_r, const float* __restrict__ w_hh_r,
    const float* __restrict__ b_ih_r, const float* __restrict__ b_hh_r,
    float* __restrict__ out)
{
    const int tid  = threadIdx.x;
    const int wid  = tid >> 6;     // 0 = consumer, 1 = producer
    const int lane = tid & 63;
    const int s    = blockIdx.x;   // batch sample

    const int  dirh = lane >> 5;           // 0 = forward half, 1 = reverse half
    const int  hl   = lane & 31;           // lane within half
    const bool valid = (hl < HH);
    const int  j     = valid ? hl : (HH - 1);   // clamp keeps loads in-bounds

    const float* __restrict__ w_ih = dirh ? w_ih_r : w_ih_f;
    const float* __restrict__ w_hh = dirh ? w_hh_r : w_hh_f;
    const float* __restrict__ b_ih = dirh ? b_ih_r : b_ih_f;
    const float* __restrict__ b_hh = dirh ? b_hh_r : b_hh_f;

    const int t0    = dirh ? (TT - 1) : 0;
    const int xstep = dirh ? -(BB * II) : (BB * II);
    const int ostep = dirh ? -(BB * 2 * HH) : (BB * 2 * HH);
    const int xbase = (t0 * BB + s) * II;

    // Row scale per gate (i,f,g,o): sigmoid rows -log2e, tanh row -2log2e.
    const float gsc[4] = { -LOG2E, -LOG2E, -2.0f * LOG2E, -LOG2E };

    __shared__ f4    ring[RS][64];       // xproj ring: [slot][lane]
    __shared__ float hstage[CH * 64];    // h history: [step-in-chunk][lane]

    if (wid == 1) {
        // ---------------- producer wave (both halves) ----------------
        f2 wih[4][5];
        float bs[4];
#pragma unroll
        for (int g = 0; g < 4; ++g) {
            const int r = g * HH + j;
#pragma unroll
            for (int k = 0; k < 5; ++k) {
                f2 w = *(const f2*)(w_ih + r * II + 2 * k);
                wih[g][k] = w * gsc[g];
            }
            bs[g] = (b_ih[r] + b_hh[r]) * gsc[g];
        }

        auto produce8 = [&](int base) {
            f2 xb[8][5];
#pragma unroll
            for (int i = 0; i < 8; ++i) {
                int u = base + i; if (u > TT - 1) u = TT - 1;   // in-bounds clamp
                const float* px = x + (xbase + u * xstep);
#pragma unroll
                for (int k = 0; k < 5; ++k) xb[i][k] = *(const f2*)(px + 2 * k);
            }
#pragma unroll
            for (int i = 0; i < 8; ++i) {
                const int u = base + i;
                if (u < TT) {
                    f4 xp;
#pragma unroll
                    for (int g = 0; g < 4; ++g) {
                        f2 p = {bs[g], 0.f};
#pragma unroll
                        for (int k = 0; k < 5; ++k) p += wih[g][k] * xb[i][k];
                        xp[g] = p[0] + p[1];
                    }
                    ring[u & (RS - 1)][lane] = xp;
                }
            }
        };

        produce8(0);              // prefill steps 0..15
        produce8(8);
        for (int chunk = 0; chunk < NCHUNK; ++chunk) {
            __syncthreads();
            const int base = (chunk + 1) * CH;   // fill next chunk's half
            produce8(base);
            produce8(base + 8);
        }
    } else {
        // ---------------- consumer wave (two scans, one per half) ----------------
        __builtin_amdgcn_s_setprio(1);

        f2 whh[4][10];
#pragma unroll
        for (int g = 0; g < 4; ++g) {
            const int r = g * HH + j;
#pragma unroll
            for (int k = 0; k < 10; ++k) {
                f2 w = *(const f2*)(w_hh + r * HH + 2 * k);
                whh[g][k] = w * gsc[g];
            }
        }

        // Dump mapping: per half, 320 elements (16 t x 20 j) over 32 lanes x 10.
        const int obase = (t0 * BB + s) * (2 * HH) + dirh * HH;
        int offd[10], lds_d[10];
#pragma unroll
        for (int q = 0; q < 10; ++q) {
            const int idx = q * 32 + hl;         // 0..319 within own half
            const int td  = idx / HH;            // 0..15
            const int jd  = idx - td * HH;       // 0..19
            offd[q]  = obase + td * ostep + jd;
            lds_d[q] = td * 64 + dirh * 32 + jd; // own half's row segment
        }

        const int hboff = dirh * 32;             // float offset of own half's h row

        f4 hb[5];
#pragma unroll
        for (int k = 0; k < 5; ++k) hb[k] = f4{0.f, 0.f, 0.f, 0.f};

        float c = 0.0f, h = 0.0f;
        int t = 0;

        for (int chunk = 0; chunk < NCHUNK; ++chunk) {
            __syncthreads();
            f4 xp = ring[t & (RS - 1)][lane];   // first step of chunk
#pragma unroll
            for (int i = 0; i < CH; ++i, ++t) {
                // ---- recurrent dots: 4 gates x 10 pk-FMA (depends on hb) ----
                f2 a0[4], a1[4];
#pragma unroll
                for (int g = 0; g < 4; ++g) { a0[g] = f2{0.f, 0.f}; a1[g] = f2{0.f, 0.f}; }
#pragma unroll
                for (int k = 0; k < 5; ++k) {
                    const f4 hv = hb[k];
                    f2 lo; lo[0] = hv[0]; lo[1] = hv[1];
                    f2 hi; hi[0] = hv[2]; hi[1] = hv[3];
#pragma unroll
                    for (int g = 0; g < 4; ++g) {
                        a0[g] += whh[g][2 * k]     * lo;
                        a1[g] += whh[g][2 * k + 1] * hi;
                    }
                }
                float u[4];
#pragma unroll
                for (int g = 0; g < 4; ++g) {
                    const f2 a = a0[g] + a1[g];
                    u[g] = (xp[g] + a[0]) + a[1];   // pre-scaled: exp2-ready
                }

                // ---- activations: sigma via rcp(1+2^u) ----
                const float ig = __builtin_amdgcn_rcpf(1.0f + fexp2(u[0]));
                const float fg = __builtin_amdgcn_rcpf(1.0f + fexp2(u[1]));
                const float sg = __builtin_amdgcn_rcpf(1.0f + fexp2(u[2]));  // sigma(2 v_g)
                const float og = __builtin_amdgcn_rcpf(1.0f + fexp2(u[3]));
                const float i2 = ig + ig;
                const float o2 = og + og;

                // ---- lane-local state update (tanh = 2 sigma - 1, FMA form) ----
                const float m = __builtin_fmaf(i2, sg, -ig);        // i * tanh(v_g)
                c = __builtin_fmaf(fg, c, m);
                const float sc_ = __builtin_amdgcn_rcpf(
                                    1.0f + fexp2(c * (-2.0f * LOG2E)));  // sigma(2c)
                h = __builtin_fmaf(o2, sc_, -og);                   // o * tanh(c)

                // ---- stage h (unconditional; clamp-lanes write unread slots) ----
                hstage[i * 64 + lane] = h;
                __builtin_amdgcn_wave_barrier();

                // ---- broadcast read of own half's 20 h (same-wave LDS in-order) ----
#pragma unroll
                for (int k = 0; k < 5; ++k)
                    hb[k] = *(const f4*)&hstage[i * 64 + hboff + 4 * k];

                // ---- ring read for next step ----
                if (i < CH - 1) xp = ring[(t + 1) & (RS - 1)][lane];
            }

            // ---- dump the chunk's 2x16x20 h block to HBM (off the chain) ----
#pragma unroll
            for (int q = 0; q < 10; ++q) {
                const float v = hstage[lds_d[q]];
                out[offd[q]] = v;
                offd[q] += CH * ostep;
            }
        }
    }
}

extern "C" void kernel_launch(void* const* d_in, const int* in_sizes, int n_in,
                              void* d_out, int out_size, void* d_ws, size_t ws_size,
                              hipStream_t stream) {
    const float* xp     = (const float*)d_in[0];
    const float* w_ih_f = (const float*)d_in[1];
    const float* w_hh_f = (const float*)d_in[2];
    const float* b_ih_f = (const float*)d_in[3];
    const float* b_hh_f = (const float*)d_in[4];
    const float* w_ih_r = (const float*)d_in[5];
    const float* w_hh_r = (const float*)d_in[6];
    const float* b_ih_r = (const float*)d_in[7];
    const float* b_hh_r = (const float*)d_in[8];
    float* outp = (float*)d_out;

    hipLaunchKernelGGL(lstm_bidir, dim3(512), dim3(128), 0, stream,
                       xp, w_ih_f, w_hh_f, b_ih_f, b_hh_f,
                       w_ih_r, w_hh_r, b_ih_r, b_hh_r, outp);
}